// Round 2
// baseline (119.746 us; speedup 1.0000x reference)
//
#include <hip/hip_runtime.h>
#include <math.h>

#define T_TOK 4096
#define DD 64
#define NLAND 8
#define NHEADS 64          // B*H = 4*16
#define SEG 512            // T_TOK / NLAND
#define NCHUNK 32          // k3v chunks per head
#define CHUNK 128          // T_TOK / NCHUNK
#define SCALE 0.125f

// workspace layout (in floats)
#define QL_OFF   0                      // [64][8][64]   = 32768
#define KL_OFF   32768                  // [64][8][64]   = 32768
#define K2_OFF   65536                  // [64][8][8]    = 4096
#define CS_OFF   69632                  // [64][8]       = 512
#define PINV_OFF 70144                  // [64][8][8]    = 4096
// scratch region, time-multiplexed:
//   phase 1: landmark partials LPQ/LPK  [4096][64] each
//   phase 2: k3v partials PA [64][32][8][64], PD [64][32][8]
#define LPQ_OFF  74240                  // 262144
#define LPK_OFF  336384                 // 262144
#define PA_OFF   74240                  // 1048576 (aliases LP after consumed)
#define PD_OFF   1122816                // 16384
#define K3V_OFF  1139200                // 32768
// total = 1171968 floats ~= 4.5 MB

// ---------------------------------------------------------------------------
// 1. Landmark partials: one block per 64-token sub-segment (4096 blocks).
//    Each block sums 64 tokens x 64 dims of q and k.
// ---------------------------------------------------------------------------
__global__ __launch_bounds__(256) void landmark_partial_kernel(
    const float* __restrict__ q, const float* __restrict__ k,
    float* __restrict__ ws) {
  int tid = threadIdx.x;
  size_t base = (size_t)blockIdx.x * (64 * DD);
  const float4* q4 = (const float4*)(q + base);
  const float4* k4 = (const float4*)(k + base);

  float4 aq = make_float4(0.f, 0.f, 0.f, 0.f);
  float4 ak = make_float4(0.f, 0.f, 0.f, 0.f);
#pragma unroll
  for (int it = 0; it < 4; ++it) {
    float4 x = q4[it * 256 + tid];
    aq.x += x.x; aq.y += x.y; aq.z += x.z; aq.w += x.w;
    float4 y = k4[it * 256 + tid];
    ak.x += y.x; ak.y += y.y; ak.z += y.z; ak.w += y.w;
  }
  __shared__ float4 redq[16][16];
  __shared__ float4 redk[16][16];
  int g = tid >> 4, d4 = tid & 15;
  redq[g][d4] = aq;
  redk[g][d4] = ak;
  __syncthreads();
  if (tid < 16) {
    float4 sq = make_float4(0.f, 0.f, 0.f, 0.f);
    float4 sk = make_float4(0.f, 0.f, 0.f, 0.f);
    for (int gg = 0; gg < 16; ++gg) {
      float4 a = redq[gg][tid];
      sq.x += a.x; sq.y += a.y; sq.z += a.z; sq.w += a.w;
      float4 b = redk[gg][tid];
      sk.x += b.x; sk.y += b.y; sk.z += b.z; sk.w += b.w;
    }
    ((float4*)(ws + LPQ_OFF + (size_t)blockIdx.x * 64))[tid] = sq;
    ((float4*)(ws + LPK_OFF + (size_t)blockIdx.x * 64))[tid] = sk;
  }
}

// ---------------------------------------------------------------------------
// 2. prep: reduce landmark partials -> q_l,k_l; compute kernel_2 softmax and
//    its column sums.  One block (512 thr) per head.
// ---------------------------------------------------------------------------
__global__ __launch_bounds__(512) void prep_kernel(float* __restrict__ ws) {
  int hb = blockIdx.x;
  int tid = threadIdx.x;
  __shared__ float qls[8][65];
  __shared__ float kls[8][65];
  __shared__ float lsm[8][9];

  int m = tid >> 6, d = tid & 63;
  float sq = 0.f, sk = 0.f;
#pragma unroll
  for (int c = 0; c < 8; ++c) {
    size_t idx = ((size_t)(hb * 8 + m) * 8 + c) * 64 + d;
    sq += ws[LPQ_OFF + idx];
    sk += ws[LPK_OFF + idx];
  }
  sq *= (1.f / (float)SEG);
  sk *= (1.f / (float)SEG);
  qls[m][d] = sq;
  kls[m][d] = sk;
  ws[QL_OFF + hb * 512 + tid] = sq;
  ws[KL_OFF + hb * 512 + tid] = sk;
  __syncthreads();

  int i = tid >> 3, j = tid & 7;
  float l = 0.f;
  if (tid < 64) {
    float dot = 0.f;
#pragma unroll
    for (int dd = 0; dd < 64; ++dd) dot += qls[i][dd] * kls[j][dd];
    l = dot * SCALE;
    lsm[i][j] = l;
  }
  __syncthreads();
  float val = 0.f;
  if (tid < 64) {
    float mx = -1e30f;
    for (int jj = 0; jj < 8; ++jj) mx = fmaxf(mx, lsm[i][jj]);
    float s = 0.f;
    for (int jj = 0; jj < 8; ++jj) s += __expf(lsm[i][jj] - mx);
    val = __expf(l - mx) / s;
    ws[K2_OFF + hb * 64 + tid] = val;
  }
  __syncthreads();
  if (tid < 64) lsm[i][j] = val;
  __syncthreads();
  if (tid < 8) {
    float cs = 0.f;
    for (int ii = 0; ii < 8; ++ii) cs += lsm[ii][tid];
    ws[CS_OFF + hb * 8 + tid] = cs;
  }
}

// ---------------------------------------------------------------------------
// 3. Newton-Schulz pseudo-inverse.  Global max over all 512 column sums,
//    then 6 iterations of 8x8 matmuls in LDS.  One block (64 thr) per head.
// ---------------------------------------------------------------------------
__global__ __launch_bounds__(64) void pinv_kernel(float* __restrict__ ws) {
  int hb = blockIdx.x;
  int tid = threadIdx.x;
  float mx = 0.f;
  for (int t = 0; t < 8; ++t) mx = fmaxf(mx, ws[CS_OFF + t * 64 + tid]);
  for (int off = 32; off; off >>= 1) mx = fmaxf(mx, __shfl_xor(mx, off));
  float inv = 1.f / mx;

  int i = tid >> 3, j = tid & 7;
  __shared__ float K[8][9], V[8][9], X[8][9], Y[8][9];
  K[i][j] = ws[K2_OFF + hb * 64 + tid];
  V[i][j] = ws[K2_OFF + hb * 64 + j * 8 + i] * inv;  // (1/max) * K^T
  __syncthreads();
  for (int it = 0; it < 6; ++it) {
    float x = 0.f;
    for (int kk = 0; kk < 8; ++kk) x += K[i][kk] * V[kk][j];
    X[i][j] = x;
    __syncthreads();
    float bm = 0.f;
    for (int kk = 0; kk < 8; ++kk) bm += X[i][kk] * X[kk][j];
    bm = 7.f * x - bm;
    Y[i][j] = bm;
    __syncthreads();
    float dm = 0.f;
    for (int kk = 0; kk < 8; ++kk) dm += X[i][kk] * Y[kk][j];
    dm = 15.f * x - dm;
    __syncthreads();
    Y[i][j] = dm;
    __syncthreads();
    float vd = 0.f;
    for (int kk = 0; kk < 8; ++kk) vd += V[i][kk] * Y[kk][j];
    float vn = 0.25f * (13.f * V[i][j] - vd);
    __syncthreads();
    V[i][j] = vn;
    __syncthreads();
  }
  ws[PINV_OFF + hb * 64 + tid] = V[i][j];
}

// ---------------------------------------------------------------------------
// 4. k3v partials: one block per (head, 128-token chunk) = 2048 blocks.
//    Stage k tile in LDS, compute exp(q_l.k_t), accumulate against v read
//    directly from global (coalesced; 4 waves share lines via L1/L2).
// ---------------------------------------------------------------------------
#define PADT 68
__global__ __launch_bounds__(256) void k3v_partial_kernel(
    const float* __restrict__ k, const float* __restrict__ v,
    float* __restrict__ ws) {
  int hb = blockIdx.x >> 5;
  int c  = blockIdx.x & 31;
  int tid = threadIdx.x;
  __shared__ float ql[8][65];
  __shared__ float kt[64][PADT];
  __shared__ float pl[64][8];

  if (tid < 128) {
    float4 x = ((const float4*)(ws + QL_OFF + hb * 512))[tid];
    int m = tid >> 4, d4 = (tid & 15) * 4;
    ql[m][d4] = x.x; ql[m][d4 + 1] = x.y; ql[m][d4 + 2] = x.z; ql[m][d4 + 3] = x.w;
  }

  size_t base = (size_t)hb * (T_TOK * DD) + (size_t)c * (CHUNK * DD);
  int m0 = tid >> 6, d0 = tid & 63;
  float a0 = 0.f, a1 = 0.f;
  float dden = 0.f;

  for (int tile = 0; tile < 2; ++tile) {
    __syncthreads();  // protects ql on tile 0, kt/pl reuse afterwards
    const float4* k4 = (const float4*)(k + base + (size_t)tile * 64 * DD);
#pragma unroll
    for (int it = 0; it < 4; ++it) {
      int f4 = it * 256 + tid;
      int t = f4 >> 4, d4 = (f4 & 15) << 2;
      float4 x = k4[f4];
      kt[t][d4] = x.x; kt[t][d4 + 1] = x.y; kt[t][d4 + 2] = x.z; kt[t][d4 + 3] = x.w;
    }
    __syncthreads();
#pragma unroll
    for (int p = 0; p < 2; ++p) {
      int idx = p * 256 + tid;
      int t = idx >> 3, m = idx & 7;
      float dot = 0.f;
#pragma unroll
      for (int d = 0; d < 64; ++d) dot += kt[t][d] * ql[m][d];
      pl[t][m] = __expf(dot * SCALE);
    }
    __syncthreads();
    {
      const float* vp = v + base + (size_t)tile * 64 * DD + d0;
      float s0 = 0.f, s1 = 0.f;
#pragma unroll
      for (int t = 0; t < 64; ++t) {
        float vv = vp[(size_t)t * 64];
        s0 += pl[t][m0] * vv;
        s1 += pl[t][m0 + 4] * vv;
      }
      a0 += s0;
      a1 += s1;
    }
    if (tid < 8) {
      float s = 0.f;
      for (int t = 0; t < 64; ++t) s += pl[t][tid];
      dden += s;
    }
  }
  ws[PA_OFF + (((size_t)hb * NCHUNK + c) * 8 + m0) * 64 + d0] = a0;
  ws[PA_OFF + (((size_t)hb * NCHUNK + c) * 8 + m0 + 4) * 64 + d0] = a1;
  if (tid < 8) ws[PD_OFF + (hb * NCHUNK + c) * 8 + tid] = dden;
}

// ---------------------------------------------------------------------------
// 5. Reduce chunk partials -> k3v[head][8][64], normalized.
// ---------------------------------------------------------------------------
__global__ __launch_bounds__(512) void k3v_reduce_kernel(float* __restrict__ ws) {
  int hb = blockIdx.x;
  int tid = threadIdx.x;
  int m = tid >> 6, d = tid & 63;
  float s = 0.f, den = 0.f;
  for (int c = 0; c < NCHUNK; ++c) {
    s += ws[PA_OFF + (((size_t)hb * NCHUNK + c) * 8 + m) * 64 + d];
    den += ws[PD_OFF + (hb * NCHUNK + c) * 8 + m];
  }
  ws[K3V_OFF + hb * 512 + tid] = s / den;
}

// ---------------------------------------------------------------------------
// 6. Output: per 64-token tile of one head:
//    w = softmax(q_t . k_l * scale)  (8-wide);  u = w @ pinv;  out = u @ k3v.
// ---------------------------------------------------------------------------
__global__ __launch_bounds__(256) void out_kernel(
    const float* __restrict__ q, float* __restrict__ out,
    const float* __restrict__ ws) {
  int hb = blockIdx.x >> 6;
  int tt = blockIdx.x & 63;
  int tid = threadIdx.x;
  __shared__ float qt[64][PADT];
  __shared__ float klh[8][65];
  __shared__ float k3v[8][65];
  __shared__ float pv[8][9];
  __shared__ float lsm[64][9];
  __shared__ float uu[64][9];

  if (tid < 128) {
    int m = tid >> 4, d4 = (tid & 15) * 4;
    float4 x = ((const float4*)(ws + KL_OFF + hb * 512))[tid];
    klh[m][d4] = x.x; klh[m][d4 + 1] = x.y; klh[m][d4 + 2] = x.z; klh[m][d4 + 3] = x.w;
    float4 y = ((const float4*)(ws + K3V_OFF + hb * 512))[tid];
    k3v[m][d4] = y.x; k3v[m][d4 + 1] = y.y; k3v[m][d4 + 2] = y.z; k3v[m][d4 + 3] = y.w;
  }
  if (tid < 64) pv[tid >> 3][tid & 7] = ws[PINV_OFF + hb * 64 + tid];

  size_t base = (size_t)hb * (T_TOK * DD) + (size_t)tt * (64 * DD);
  const float4* q4 = (const float4*)(q + base);
#pragma unroll
  for (int it = 0; it < 4; ++it) {
    int f4 = it * 256 + tid;
    int t = f4 >> 4, d4 = (f4 & 15) << 2;
    float4 x = q4[f4];
    qt[t][d4] = x.x; qt[t][d4 + 1] = x.y; qt[t][d4 + 2] = x.z; qt[t][d4 + 3] = x.w;
  }
  __syncthreads();
#pragma unroll
  for (int p = 0; p < 2; ++p) {
    int idx = p * 256 + tid;
    int t = idx >> 3, m = idx & 7;
    float dot = 0.f;
#pragma unroll
    for (int d = 0; d < 64; ++d) dot += qt[t][d] * klh[m][d];
    lsm[t][m] = dot * SCALE;
  }
  __syncthreads();
  if (tid < 64) {
    int t = tid;
    float l[8];
    float mx = -1e30f;
#pragma unroll
    for (int m = 0; m < 8; ++m) { l[m] = lsm[t][m]; mx = fmaxf(mx, l[m]); }
    float s = 0.f;
#pragma unroll
    for (int m = 0; m < 8; ++m) { l[m] = __expf(l[m] - mx); s += l[m]; }
    float is = 1.f / s;
#pragma unroll
    for (int m = 0; m < 8; ++m) l[m] *= is;
#pragma unroll
    for (int j = 0; j < 8; ++j) {
      float u = 0.f;
#pragma unroll
      for (int m = 0; m < 8; ++m) u += l[m] * pv[m][j];
      uu[t][j] = u;
    }
  }
  __syncthreads();
  float4* o4 = (float4*)(out + base);
#pragma unroll
  for (int it = 0; it < 4; ++it) {
    int f4 = it * 256 + tid;
    int t = f4 >> 4, d4 = (f4 & 15) << 2;
    float r0 = 0.f, r1 = 0.f, r2 = 0.f, r3 = 0.f;
#pragma unroll
    for (int m = 0; m < 8; ++m) {
      float u = uu[t][m];
      r0 += u * k3v[m][d4];
      r1 += u * k3v[m][d4 + 1];
      r2 += u * k3v[m][d4 + 2];
      r3 += u * k3v[m][d4 + 3];
    }
    o4[f4] = make_float4(r0, r1, r2, r3);
  }
}

// ---------------------------------------------------------------------------
extern "C" void kernel_launch(void* const* d_in, const int* in_sizes, int n_in,
                              void* d_out, int out_size, void* d_ws, size_t ws_size,
                              hipStream_t stream) {
  const float* q = (const float*)d_in[0];
  const float* k = (const float*)d_in[1];
  const float* v = (const float*)d_in[2];
  float* out = (float*)d_out;
  float* ws = (float*)d_ws;

  landmark_partial_kernel<<<NHEADS * 64, 256, 0, stream>>>(q, k, ws);
  prep_kernel<<<NHEADS, 512, 0, stream>>>(ws);
  k3v_partial_kernel<<<NHEADS * NCHUNK, 256, 0, stream>>>(k, v, ws);
  pinv_kernel<<<NHEADS, 64, 0, stream>>>(ws);
  k3v_reduce_kernel<<<NHEADS, 512, 0, stream>>>(ws);
  out_kernel<<<NHEADS * 64, 256, 0, stream>>>(q, out, ws);
}

// Round 3
// 93.047 us; speedup vs baseline: 1.2869x; 1.2869x over previous
//
#include <hip/hip_runtime.h>
#include <math.h>

#define T_TOK 4096
#define DD 64
#define NHEADS 64          // B*H = 4*16
#define SEG 512            // tokens per landmark segment
#define NCHUNK 32          // 128-token chunks per head
#define CHUNK 128
#define TILE 32            // tokens staged per LDS tile in k3v
#define SCALE 0.125f

// workspace layout (in floats)
#define QL_OFF   0                      // [64][8][64]
#define KL_OFF   32768                  // [64][8][64]
#define K2_OFF   65536                  // [64][8][8]
#define CS_OFF   69632                  // [64][8]
#define PINV_OFF 70144                  // [64][8][8]
#define LPQ_OFF  74240                  // [2048][64] q landmark partials
#define KP_OFF   205312                 // [2048][64] k landmark partials
#define PA_OFF   336384                 // [64][32][8][64] k3v partials
#define PD_OFF   1384960                // [64][32][8] denominators
#define W2_OFF   1401344                // [64][8][64] pinv @ k3v
// end = 1434112 floats ~= 5.74 MB

// ---------------------------------------------------------------------------
// 1. q landmark partials: one block per 128 tokens (2048 blocks).
// ---------------------------------------------------------------------------
__global__ __launch_bounds__(256) void qsum_kernel(
    const float* __restrict__ q, float* __restrict__ ws) {
  int tid = threadIdx.x;
  const float4* q4 = (const float4*)q + (size_t)blockIdx.x * 2048;
  float4 a = make_float4(0.f, 0.f, 0.f, 0.f);
#pragma unroll
  for (int it = 0; it < 8; ++it) {
    float4 x = q4[it * 256 + tid];
    a.x += x.x; a.y += x.y; a.z += x.z; a.w += x.w;
  }
  __shared__ float4 red[16][17];
  red[tid >> 4][tid & 15] = a;
  __syncthreads();
  if (tid < 16) {
    float4 s = make_float4(0.f, 0.f, 0.f, 0.f);
#pragma unroll
    for (int g = 0; g < 16; ++g) {
      float4 r = red[g][tid];
      s.x += r.x; s.y += r.y; s.z += r.z; s.w += r.w;
    }
    ((float4*)(ws + LPQ_OFF))[blockIdx.x * 16 + tid] = s;
  }
}

// ---------------------------------------------------------------------------
// 2. Reduce q partials -> q_l.  64 blocks x 512 threads.
// ---------------------------------------------------------------------------
__global__ __launch_bounds__(512) void prepq_kernel(float* __restrict__ ws) {
  int hb = blockIdx.x, tid = threadIdx.x;
  int m = tid >> 6, d = tid & 63;
  float s = 0.f;
#pragma unroll
  for (int c2 = 0; c2 < 4; ++c2)
    s += ws[LPQ_OFF + (size_t)(hb * 32 + m * 4 + c2) * 64 + d];
  ws[QL_OFF + hb * 512 + tid] = s * (1.f / (float)SEG);
}

// ---------------------------------------------------------------------------
// 3. k3v partials + k landmark partials.  One block per (head, 128-chunk).
//    k and v staged in 32-token LDS tiles (float4); denominators via shfl.
// ---------------------------------------------------------------------------
__global__ __launch_bounds__(256) void k3v_kernel(
    const float* __restrict__ k, const float* __restrict__ v,
    float* __restrict__ ws) {
  int hb = blockIdx.x >> 5, c = blockIdx.x & 31;
  int tid = threadIdx.x;
  int w = tid >> 6, lane = tid & 63;
  __shared__ float ql[8][68];
  __shared__ float kt[TILE][68];
  __shared__ float vt[TILE][68];
  __shared__ float pl[TILE][9];
  __shared__ float denp[4][8];

  if (tid < 128) {
    float4 x = ((const float4*)(ws + QL_OFF))[hb * 128 + tid];
    *(float4*)&ql[tid >> 4][(tid & 15) * 4] = x;
  }
  size_t base4 = ((size_t)hb * T_TOK + (size_t)c * CHUNK) * 16;  // float4 units
  float a0 = 0.f, a1 = 0.f, dden = 0.f, ksum = 0.f;

  for (int tile = 0; tile < 4; ++tile) {
    __syncthreads();   // ql ready (tile 0); prev accumulate done
    const float4* k4 = (const float4*)k + base4 + tile * TILE * 16;
    const float4* v4 = (const float4*)v + base4 + tile * TILE * 16;
    {
      float4 x0 = k4[tid], x1 = k4[tid + 256];
      float4 y0 = v4[tid], y1 = v4[tid + 256];
      *(float4*)&kt[tid >> 4][(tid & 15) * 4] = x0;
      *(float4*)&kt[(tid + 256) >> 4][(tid & 15) * 4] = x1;
      *(float4*)&vt[tid >> 4][(tid & 15) * 4] = y0;
      *(float4*)&vt[(tid + 256) >> 4][(tid & 15) * 4] = y1;
    }
    __syncthreads();
    {
      int t = tid >> 3, m = tid & 7;
      const float4* kr = (const float4*)&kt[t][0];
      const float4* qr = (const float4*)&ql[m][0];
      float dot = 0.f;
#pragma unroll
      for (int d4 = 0; d4 < 16; ++d4) {
        float4 kk = kr[d4], qq = qr[d4];
        dot += kk.x * qq.x + kk.y * qq.y + kk.z * qq.z + kk.w * qq.w;
      }
      float p = __expf(dot * SCALE);
      pl[t][m] = p;
      float r = p;
      r += __shfl_xor(r, 8);
      r += __shfl_xor(r, 16);
      r += __shfl_xor(r, 32);
      if (lane < 8) denp[w][lane] = r;   // sum over this wave's 8 tokens
    }
    __syncthreads();
    {
#pragma unroll
      for (int t = 0; t < TILE; ++t) {
        float vv = vt[t][lane];
        a0 += pl[t][w] * vv;
        a1 += pl[t][w + 4] * vv;
      }
      if (w == 0) {
#pragma unroll
        for (int t = 0; t < TILE; ++t) ksum += kt[t][lane];
      }
      if (tid < 8)
        dden += denp[0][tid] + denp[1][tid] + denp[2][tid] + denp[3][tid];
    }
  }
  ws[PA_OFF + (((size_t)hb * NCHUNK + c) * 8 + w) * 64 + lane] = a0;
  ws[PA_OFF + (((size_t)hb * NCHUNK + c) * 8 + w + 4) * 64 + lane] = a1;
  if (tid < 8) ws[PD_OFF + (hb * NCHUNK + c) * 8 + tid] = dden;
  if (tid < 64) ws[KP_OFF + (size_t)(hb * NCHUNK + c) * 64 + tid] = ksum;
}

// ---------------------------------------------------------------------------
// 4. Reduce k partials -> k_l; kernel_2 softmax + column sums.
// ---------------------------------------------------------------------------
__global__ __launch_bounds__(512) void prepk_kernel(float* __restrict__ ws) {
  int hb = blockIdx.x, tid = threadIdx.x;
  __shared__ float qls[8][68];
  __shared__ float kls[8][68];
  __shared__ float ee[8][9];
  int m = tid >> 6, d = tid & 63;
  float s = 0.f;
#pragma unroll
  for (int c2 = 0; c2 < 4; ++c2)
    s += ws[KP_OFF + (size_t)(hb * 32 + m * 4 + c2) * 64 + d];
  s *= (1.f / (float)SEG);
  kls[m][d] = s;
  ws[KL_OFF + hb * 512 + tid] = s;
  qls[m][d] = ws[QL_OFF + hb * 512 + tid];
  __syncthreads();
  if (tid < 64) {
    int i = tid >> 3, j = tid & 7;
    float dot = 0.f;
#pragma unroll
    for (int dd = 0; dd < 64; ++dd) dot += qls[i][dd] * kls[j][dd];
    ee[i][j] = __expf(dot * SCALE);   // logits tiny: no max needed
  }
  __syncthreads();
  if (tid < 64) {
    int i = tid >> 3, j = tid & 7;
    float ssum = 0.f;
#pragma unroll
    for (int jj = 0; jj < 8; ++jj) ssum += ee[i][jj];
    ws[K2_OFF + hb * 64 + tid] = ee[i][j] / ssum;
  }
  if (tid < 8) {
    float cs = 0.f;
    for (int ii = 0; ii < 8; ++ii) {
      float ssum = 0.f;
#pragma unroll
      for (int jj = 0; jj < 8; ++jj) ssum += ee[ii][jj];
      cs += ee[ii][tid] / ssum;
    }
    ws[CS_OFF + hb * 8 + tid] = cs;
  }
}

// ---------------------------------------------------------------------------
// 5. Newton-Schulz pseudo-inverse (global max over all 512 column sums).
// ---------------------------------------------------------------------------
__global__ __launch_bounds__(64) void pinv_kernel(float* __restrict__ ws) {
  int hb = blockIdx.x;
  int tid = threadIdx.x;
  float mx = 0.f;
  for (int t = 0; t < 8; ++t) mx = fmaxf(mx, ws[CS_OFF + t * 64 + tid]);
  for (int off = 32; off; off >>= 1) mx = fmaxf(mx, __shfl_xor(mx, off));
  float inv = 1.f / mx;

  int i = tid >> 3, j = tid & 7;
  __shared__ float K[8][9], V[8][9], X[8][9], Y[8][9];
  K[i][j] = ws[K2_OFF + hb * 64 + tid];
  V[i][j] = ws[K2_OFF + hb * 64 + j * 8 + i] * inv;  // (1/max) * K^T
  __syncthreads();
  for (int it = 0; it < 6; ++it) {
    float x = 0.f;
    for (int kk = 0; kk < 8; ++kk) x += K[i][kk] * V[kk][j];
    X[i][j] = x;
    __syncthreads();
    float bm = 0.f;
    for (int kk = 0; kk < 8; ++kk) bm += X[i][kk] * X[kk][j];
    bm = 7.f * x - bm;
    Y[i][j] = bm;
    __syncthreads();
    float dm = 0.f;
    for (int kk = 0; kk < 8; ++kk) dm += X[i][kk] * Y[kk][j];
    dm = 15.f * x - dm;
    __syncthreads();
    Y[i][j] = dm;
    __syncthreads();
    float vd = 0.f;
    for (int kk = 0; kk < 8; ++kk) vd += V[i][kk] * Y[kk][j];
    float vn = 0.25f * (13.f * V[i][j] - vd);
    __syncthreads();
    V[i][j] = vn;
    __syncthreads();
  }
  ws[PINV_OFF + hb * 64 + tid] = V[i][j];
}

// ---------------------------------------------------------------------------
// 6. Reduce k3v partials, normalize, and fold in pinv: W2 = pinv @ k3v.
// ---------------------------------------------------------------------------
__global__ __launch_bounds__(512) void redw2_kernel(float* __restrict__ ws) {
  int hb = blockIdx.x, tid = threadIdx.x;
  __shared__ float k3vs[8][68];
  __shared__ float pv[8][9];
  int m = tid >> 6, d = tid & 63;
  float s = 0.f, den = 0.f;
  for (int c = 0; c < NCHUNK; ++c) {
    s += ws[PA_OFF + (((size_t)hb * NCHUNK + c) * 8 + m) * 64 + d];
    den += ws[PD_OFF + (hb * NCHUNK + c) * 8 + m];
  }
  k3vs[m][d] = s / den;
  if (tid < 64) pv[tid >> 3][tid & 7] = ws[PINV_OFF + hb * 64 + tid];
  __syncthreads();
  float o = 0.f;
#pragma unroll
  for (int j = 0; j < 8; ++j) o += pv[m][j] * k3vs[j][d];
  ws[W2_OFF + hb * 512 + tid] = o;
}

// ---------------------------------------------------------------------------
// 7. Output: per 64-token tile: p = exp(q_t . k_l * scale); out = (p/Σp) @ W2.
// ---------------------------------------------------------------------------
__global__ __launch_bounds__(256) void out_kernel(
    const float* __restrict__ q, float* __restrict__ out,
    const float* __restrict__ ws) {
  int hb = blockIdx.x >> 6, tt = blockIdx.x & 63;
  int tid = threadIdx.x;
  __shared__ float qt[64][68];
  __shared__ float klh[8][68];
  __shared__ float w2s[8][68];
  __shared__ float pl[64][9];

  if (tid < 128) {
    float4 x = ((const float4*)(ws + KL_OFF))[hb * 128 + tid];
    *(float4*)&klh[tid >> 4][(tid & 15) * 4] = x;
    float4 y = ((const float4*)(ws + W2_OFF))[hb * 128 + tid];
    *(float4*)&w2s[tid >> 4][(tid & 15) * 4] = y;
  }
  size_t base4 = ((size_t)hb * T_TOK + (size_t)tt * 64) * 16;
  const float4* q4 = (const float4*)q + base4;
#pragma unroll
  for (int it = 0; it < 4; ++it) {
    int f4 = it * 256 + tid;
    float4 x = q4[f4];
    *(float4*)&qt[f4 >> 4][(f4 & 15) * 4] = x;
  }
  __syncthreads();
#pragma unroll
  for (int p = 0; p < 2; ++p) {
    int idx = p * 256 + tid;
    int t = idx >> 3, m = idx & 7;
    const float4* qr = (const float4*)&qt[t][0];
    const float4* kr = (const float4*)&klh[m][0];
    float dot = 0.f;
#pragma unroll
    for (int d4 = 0; d4 < 16; ++d4) {
      float4 a = qr[d4], b = kr[d4];
      dot += a.x * b.x + a.y * b.y + a.z * b.z + a.w * b.w;
    }
    pl[t][m] = __expf(dot * SCALE);   // logits tiny: no max needed
  }
  __syncthreads();
  float4* o4 = (float4*)out + base4;
#pragma unroll
  for (int i = 0; i < 4; ++i) {
    int t = i * 16 + (tid >> 4);
    int qd = tid & 15;
    float p0 = pl[t][0], p1 = pl[t][1], p2 = pl[t][2], p3 = pl[t][3];
    float p4 = pl[t][4], p5 = pl[t][5], p6 = pl[t][6], p7 = pl[t][7];
    float inv = 1.f / (p0 + p1 + p2 + p3 + p4 + p5 + p6 + p7);
    float4 acc = make_float4(0.f, 0.f, 0.f, 0.f);
    float pm[8] = {p0, p1, p2, p3, p4, p5, p6, p7};
#pragma unroll
    for (int m2 = 0; m2 < 8; ++m2) {
      float w = pm[m2] * inv;
      float4 wv = *(const float4*)&w2s[m2][qd * 4];
      acc.x += w * wv.x; acc.y += w * wv.y; acc.z += w * wv.z; acc.w += w * wv.w;
    }
    o4[i * 256 + tid] = acc;   // wave-contiguous 1 KB stores
  }
}

// ---------------------------------------------------------------------------
extern "C" void kernel_launch(void* const* d_in, const int* in_sizes, int n_in,
                              void* d_out, int out_size, void* d_ws, size_t ws_size,
                              hipStream_t stream) {
  const float* q = (const float*)d_in[0];
  const float* k = (const float*)d_in[1];
  const float* v = (const float*)d_in[2];
  float* out = (float*)d_out;
  float* ws = (float*)d_ws;

  qsum_kernel<<<2048, 256, 0, stream>>>(q, ws);
  prepq_kernel<<<NHEADS, 512, 0, stream>>>(ws);
  k3v_kernel<<<NHEADS * NCHUNK, 256, 0, stream>>>(k, v, ws);
  prepk_kernel<<<NHEADS, 512, 0, stream>>>(ws);
  pinv_kernel<<<NHEADS, 64, 0, stream>>>(ws);
  redw2_kernel<<<NHEADS, 512, 0, stream>>>(ws);
  out_kernel<<<NHEADS * 64, 256, 0, stream>>>(q, out, ws);
}